// Round 4
// baseline (206.203 us; speedup 1.0000x reference)
//
#include <hip/hip_runtime.h>
#include <math.h>

// Problem constants (fixed by reference)
#define GRIDN   14
#define BOXN    2
#define LABELN  20
#define ALL_BOX 10          // 5*BOXN
#define CCH     30          // ALL_BOX + LABELN channels per cell

// R11: kill the vmcnt(0) drain. R7-R10 post-mortems: every variant lands at
// ~2.5-2.8 TB/s delivered because __syncthreads() == "s_waitcnt vmcnt(0)
// lgkmcnt(0); s_barrier" -- each iteration force-drains ALL in-flight
// prefetches and convoys the block's 4 waves (13,500 cyc/iter to move
// 61 KB/CU; VALUBusy 8%). Occupancy (R8: 4x waves, worse), barrier position
// (R10: +5%), and pattern (prior rounds) all failed to move it.
// Fix = guide's T3/T4 minimum 2-phase form:
//  - raw __builtin_amdgcn_s_barrier() + manual "s_waitcnt lgkmcnt(0)":
//    orders the LDS staging across waves (all the barrier MUST order) but
//    never drains vmcnt -- global prefetches land in private VGPRs.
//  - depth-2 register prefetch (R0/R1): the ds_write of tile t's registers
//    gets a compiler-inserted COUNTED vmcnt wait (only tile t's 8 loads),
//    while tile t+1's loads stay in flight. Each wave keeps ~1-2 tile-loads
//    (8-15 KB) outstanding continuously instead of 8 KB at ~40% duty.
// Buffer safety (unchanged from R10, one barrier/iter): compute(k) precedes
// write(k+1) in program order, write(k+1) precedes barrier(k+1); any write
// to buf[p] at iter k+2 is therefore after every wave's reads at iter k.
#define TCELLS  128         // cells per tile (2 LDS buffers fit)
#define TF4     960         // float4 per tensor per tile (128*30/4)
#define VTOT    1920        // float4 per tile (preds+truths)
#define NREG    8           // ceil(VTOT/256) register-prefetch slots
#define PBLOCKS 512         // persistent blocks (2/CU, LDS-limited)

typedef float vfloat4 __attribute__((ext_vector_type(4)));

__global__ void yolo_zero_kernel(float* out, int n) {
    int i = blockIdx.x * blockDim.x + threadIdx.x;
    if (i < n) out[i] = 0.0f;
}

// Validated per-cell loss math (absmax 0 in rounds 1-10). Unchanged.
__device__ __forceinline__ float cell_loss(const float* p, const float* t) {
#pragma clang fp contract(off)
    const float CELL = (float)(1.0 / (double)GRIDN);

    const float tx = t[0], ty = t[1], tw = t[2], th_ = t[3], tconf = t[4];
    const bool obj = tconf > 0.0f;

    const float tcx = CELL * tx, tcy = CELL * ty;
    const float thx = tw * 0.5f, thy = th_ * 0.5f;
    const float tltx = tcx - thx, tlty = tcy - thy;
    const float trbx = tcx + thx, trby = tcy + thy;
    const float ta = (trbx - tltx) * (trby - tlty);

    float iou[BOXN], conf[BOXN];
#pragma unroll
    for (int b = 0; b < BOXN; ++b) {
        const float bx = p[b * 5 + 0], by = p[b * 5 + 1];
        const float bw = p[b * 5 + 2], bh = p[b * 5 + 3];
        conf[b] = p[b * 5 + 4];
        const float pcx = CELL * bx, pcy = CELL * by;
        const float phx = bw * 0.5f, phy = bh * 0.5f;
        const float pltx = pcx - phx, plty = pcy - phy;
        const float prbx = pcx + phx, prby = pcy + phy;
        const float ltx = fmaxf(pltx, tltx), lty = fmaxf(plty, tlty);
        const float rbx = fminf(prbx, trbx), rby = fminf(prby, trby);
        const float whx = fmaxf(rbx - ltx, 0.0f);
        const float why = fmaxf(rby - lty, 0.0f);
        const float inter = whx * why;
        const float pa = (prbx - pltx) * (prby - plty);
        iou[b] = inter / (pa + ta - inter);
    }

    const float max_iou = fmaxf(iou[0], iou[1]);
    bool r1;
    if (iou[0] == iou[1]) r1 = !(conf[0] >= conf[1]);
    else                  r1 = !(iou[0] > iou[1]);

    const float rx = r1 ? p[5] : p[0];
    const float ry = r1 ? p[6] : p[1];
    const float rw = r1 ? p[7] : p[2];
    const float rh = r1 ? p[8] : p[3];
    const float rc = r1 ? p[9] : p[4];

    const float dcx = rx - tx;
    const float dcy = ry - ty;
    const float center = dcx * dcx + dcy * dcy;

    const float dsx = sqrtf(rw) - sqrtf(tw);
    const float dsy = sqrtf(rh) - sqrtf(th_);
    const float size = dsx * dsx + dsy * dsy;

    const float dconf = rc - max_iou;
    const float conf_resp = dconf * dconf;

    const float c_other = r1 ? conf[0] : conf[1];
    const float conf_noresp = c_other * c_other;

    const float conf_noobj = conf[0] * conf[0] + conf[1] * conf[1];

    float label = 0.0f;
#pragma unroll
    for (int k = ALL_BOX; k < CCH; ++k) {
        const float d = p[k] - t[k];
        label += d * d;
    }

    const float w  = obj ? 1.0f : 0.0f;
    const float nw = obj ? 0.0f : 1.0f;
    return w * (5.0f * (center + size) + conf_resp + 0.5f * conf_noresp + label)
         + nw * (0.5f * conf_noobj);
}

// Lane-contiguous float4 tile-slice load (virtual idx: [0,TF4)=preds,
// [TF4,VTOT)=truths). Identical idiom to the passing R7/R10 kernels.
#define LOAD_SLICE(Rdst, t)                                                  \
    do {                                                                     \
        const int g_ = (t) * TF4;                                            \
        _Pragma("unroll")                                                    \
        for (int i_ = 0; i_ < NREG; ++i_) {                                  \
            const int idx_ = i_ * 256 + tid;                                 \
            if (idx_ < VTOT)                                                 \
                Rdst[i_] = (idx_ < TF4) ? pp[g_ + idx_]                      \
                                        : tp[g_ + (idx_ - TF4)];             \
        }                                                                    \
    } while (0)

#define STORE_SLICE(Rsrc, buf)                                               \
    do {                                                                     \
        _Pragma("unroll")                                                    \
        for (int i_ = 0; i_ < NREG; ++i_) {                                  \
            const int idx_ = i_ * 256 + tid;                                 \
            if (idx_ < VTOT) (buf)[idx_] = Rsrc[i_];                         \
        }                                                                    \
    } while (0)

__global__ __launch_bounds__(256, 2) void yolo_loss_kernel(
    const float* __restrict__ preds,
    const float* __restrict__ truths,
    float* __restrict__ out,
    int ntiles)
{
#pragma clang fp contract(off)
    __shared__ vfloat4 sbuf[2 * VTOT];  // 61,440 B -> 2 blocks/CU
    __shared__ float wsum[4];

    const int tid  = threadIdx.x;
    const int wave = tid >> 6;
    const int lane = tid & 63;

    const vfloat4* pp = (const vfloat4*)preds;
    const vfloat4* tp = (const vfloat4*)truths;

    // Depth-2 register pipeline: two named arrays (never runtime-indexed --
    // runtime-indexed ext_vector arrays go to scratch).
    vfloat4 R0[NREG], R1[NREG];
    int t = blockIdx.x;

    if (t < ntiles)           LOAD_SLICE(R0, t);
    if (t + PBLOCKS < ntiles) LOAD_SLICE(R1, t + PBLOCKS);

    float acc = 0.0f;
    int k = 0;
    for (; t < ntiles; t += PBLOCKS, ++k) {
        vfloat4* buf = sbuf + (k & 1) * VTOT;

        // Stage tile t's registers. Compiler inserts a COUNTED vmcnt wait
        // here (only tile t's loads); the other depth's loads stay in flight.
        if (k & 1) STORE_SLICE(R1, buf);
        else       STORE_SLICE(R0, buf);

        // LDS-only fence + raw barrier: cross-wave visibility of buf without
        // draining vmcnt (the whole point of R11).
        asm volatile("s_waitcnt lgkmcnt(0)" ::: "memory");
        __builtin_amdgcn_s_barrier();
        __builtin_amdgcn_sched_barrier(0);

        // Refill the slot just consumed with tile t+2*PBLOCKS.
        const int t2 = t + 2 * PBLOCKS;
        if (t2 < ntiles) {
            if (k & 1) LOAD_SLICE(R1, t2);
            else       LOAD_SLICE(R0, t2);
        }

        // Compute tile t. No barrier after -> next iteration's write targets
        // the OTHER buffer; reuse of this one is fenced by the next barrier.
        if (tid < TCELLS) {
            const float* sf = (const float*)buf;
            acc += cell_loss(sf + tid * CCH, sf + TF4 * 4 + tid * CCH);
        }
    }

    // Per-thread acc -> wave shuffle -> LDS across waves -> one atomic/block.
#pragma unroll
    for (int off = 32; off > 0; off >>= 1) acc += __shfl_down(acc, off, 64);
    if (lane == 0) wsum[wave] = acc;
    __syncthreads();
    if (tid == 0) {
        const float s = (wsum[0] + wsum[1]) + (wsum[2] + wsum[3]);
        atomicAdd(out, s * (1.0f / 4096.0f));
    }
}

extern "C" void kernel_launch(void* const* d_in, const int* in_sizes, int n_in,
                              void* d_out, int out_size, void* d_ws, size_t ws_size,
                              hipStream_t stream) {
    const float* preds  = (const float*)d_in[0];
    const float* truths = (const float*)d_in[1];
    float* out = (float*)d_out;

    const int ncells = in_sizes[0] / CCH;      // 802816
    const int ntiles = ncells / TCELLS;        // 6272 (exact)

    yolo_zero_kernel<<<(out_size + 255) / 256, 256, 0, stream>>>(out, out_size);
    yolo_loss_kernel<<<PBLOCKS, 256, 0, stream>>>(preds, truths, out, ntiles);
}